// Round 5
// baseline (106.952 us; speedup 1.0000x reference)
//
#include <hip/hip_runtime.h>
#include <stddef.h>

typedef unsigned short u16;
typedef unsigned int u32;
typedef __attribute__((ext_vector_type(4))) float f32x4;
typedef __attribute__((ext_vector_type(8))) u16 u16x8;
typedef __attribute__((ext_vector_type(4))) u16 u16x4;
typedef __attribute__((ext_vector_type(8))) short s16x8;
typedef __attribute__((ext_vector_type(2))) u32 u32x2;
typedef __attribute__((ext_vector_type(4))) u32 u32x4;

#define MFMA16 __builtin_amdgcn_mfma_f32_16x16x32_bf16

__device__ __forceinline__ float bf2f(u16 u) { return __uint_as_float(((u32)u) << 16); }
__device__ __forceinline__ u16 f2bf(float f) {
  u32 u = __float_as_uint(f);
  return (u16)((u + 0x7FFFu + ((u >> 16) & 1u)) >> 16);
}
__device__ __forceinline__ u32 cvt_pk_bf16(float lo, float hi) {
  u32 r; asm("v_cvt_pk_bf16_f32 %0, %1, %2" : "=v"(r) : "v"(lo), "v"(hi)); return r;
}

union frag_u { u32x4 u; s16x8 s; };

// B=32, T=500, C=256, H=8, d=32
// ws (32,768,000 B):
//   [0         ..16,384,000) qkbuf [16000][512] bf16 (Q | K)   (later: WtP)
//   [16,384,000..24,576,000) vt    [32][256][500] bf16 (V^T)
//   [24,576,000..32,768,000) ctx   [16000][256] bf16           (early: WtA)
// WtA (768x256 bf16, 394 KB) lives in the ctx region until attn_value runs.
// WtP (256x256 bf16, 131 KB) lives in the qkbuf region after attn_value.

// ---------------------------------------------------------------------------
// W transpose: Wt[n][k] (bf16) = W[k][n] (f32). Tile 64x64.
__global__ __launch_bounds__(256) void transpose_w(
    const float* __restrict__ W, u16* __restrict__ Wt, int K, int N)
{
  __shared__ u16 T[64][72];
  const int tid = threadIdx.x;
  const int k0 = blockIdx.x * 64, n0 = blockIdx.y * 64;
#pragma unroll
  for (int it = 0; it < 4; ++it) {
    const int r = it * 16 + (tid >> 4);
    const int c = (tid & 15) * 4;
    f32x4 v = *(const f32x4*)&W[(size_t)(k0 + r) * N + n0 + c];
    u16x4 o;
    o[0] = f2bf(v[0]); o[1] = f2bf(v[1]); o[2] = f2bf(v[2]); o[3] = f2bf(v[3]);
    *(u16x4*)&T[r][c] = o;
  }
  __syncthreads();
#pragma unroll
  for (int it = 0; it < 4; ++it) {
    const int n = it * 16 + (tid >> 4);
    const int kc = (tid & 15) * 4;
    u16x4 o;
    o[0] = T[kc + 0][n]; o[1] = T[kc + 1][n];
    o[2] = T[kc + 2][n]; o[3] = T[kc + 3][n];
    *(u16x4*)&Wt[(size_t)(n0 + n) * K + k0 + kc] = o;
  }
}

// ---------------------------------------------------------------------------
// Kernel 1: qkv GEMM, A-stationary. 512 thr = 8 waves (wm=w>>2, wn=w&3).
// Block = 64 rows x all 768 cols. A staged once (f32->bf16) in LDS, A-frags
// hoisted to registers; B-frags direct 16B loads from WtA (L2-resident).
__global__ __launch_bounds__(512, 2) void gemm_qkv(
    const float* __restrict__ x, const u16* __restrict__ WtA,
    const float* __restrict__ bias, u16* __restrict__ qkbuf, u16* __restrict__ vt)
{
  __shared__ u16 As[64][264];
  const int tid = threadIdx.x;
  const int lane = tid & 63;
  const int w = tid >> 6;
  const int cl = lane & 15, g = lane >> 4;
  const int wm = w >> 2, wn = w & 3;
  const int m0 = blockIdx.x * 64;

  // stage x panel -> bf16 LDS (read x exactly once)
#pragma unroll
  for (int it = 0; it < 4; ++it) {
    const int ci = tid + it * 512;          // 2048 chunks of 8
    const int row = ci >> 5;
    const int c8 = (ci & 31) * 8;
    f32x4 lo = *(const f32x4*)&x[(size_t)(m0 + row) * 256 + c8];
    f32x4 hi = *(const f32x4*)&x[(size_t)(m0 + row) * 256 + c8 + 4];
    u32x4 p;
    p[0] = cvt_pk_bf16(lo[0], lo[1]); p[1] = cvt_pk_bf16(lo[2], lo[3]);
    p[2] = cvt_pk_bf16(hi[0], hi[1]); p[3] = cvt_pk_bf16(hi[2], hi[3]);
    *(u32x4*)&As[row][c8] = p;
  }
  __syncthreads();

  // A-fragments to registers (one-time)
  s16x8 af[2][8];
#pragma unroll
  for (int mi = 0; mi < 2; ++mi)
#pragma unroll
    for (int kt = 0; kt < 8; ++kt)
      af[mi][kt] = *(const s16x8*)&As[wm * 32 + mi * 16 + cl][kt * 32 + g * 8];

#pragma unroll 1
  for (int nc = 0; nc < 3; ++nc) {
    const int n0 = wn * 192 + nc * 64;
    f32x4 acc[2][4];
#pragma unroll
    for (int mi = 0; mi < 2; ++mi)
#pragma unroll
      for (int ni = 0; ni < 4; ++ni) acc[mi][ni] = (f32x4){0.f, 0.f, 0.f, 0.f};
#pragma unroll
    for (int kt = 0; kt < 8; ++kt) {
      s16x8 bf[4];
#pragma unroll
      for (int ni = 0; ni < 4; ++ni)
        bf[ni] = *(const s16x8*)&WtA[(size_t)(n0 + ni * 16 + cl) * 256 + kt * 32 + g * 8];
#pragma unroll
      for (int mi = 0; mi < 2; ++mi)
#pragma unroll
        for (int ni = 0; ni < 4; ++ni)
          acc[mi][ni] = MFMA16(af[mi][kt], bf[ni], acc[mi][ni], 0, 0, 0);
    }
    float bb[4];
#pragma unroll
    for (int ni = 0; ni < 4; ++ni) bb[ni] = bias[n0 + ni * 16 + cl];
    if (n0 < 512) {
#pragma unroll
      for (int mi = 0; mi < 2; ++mi)
#pragma unroll
        for (int ni = 0; ni < 4; ++ni)
#pragma unroll
          for (int r = 0; r < 4; ++r) {
            const int m = m0 + wm * 32 + mi * 16 + g * 4 + r;
            qkbuf[(size_t)m * 512 + n0 + ni * 16 + cl] = f2bf(acc[mi][ni][r] + bb[ni]);
          }
    } else {
#pragma unroll
      for (int mi = 0; mi < 2; ++mi)
#pragma unroll
        for (int ni = 0; ni < 4; ++ni) {
          const int cb = n0 - 512 + ni * 16 + cl;
#pragma unroll
          for (int r = 0; r < 4; ++r) {
            const int m = m0 + wm * 32 + mi * 16 + g * 4 + r;
            const int b2 = m / 500;
            const int t2 = m - b2 * 500;
            vt[(size_t)(b2 * 256 + cb) * 500 + t2] = f2bf(acc[mi][ni][r] + bb[ni]);
          }
        }
    }
  }
}

// ---------------------------------------------------------------------------
// Kernel 2: pred GEMM. pred[b] = sigmoid( (Q diag(pw*scale)) @ K^T ), f32 out.
__global__ __launch_bounds__(256) void pred_gemm(
    const u16* __restrict__ qk, const float* __restrict__ pw_g,
    float* __restrict__ pred)
{
  const int tid = threadIdx.x;
  const int lane = tid & 63;
  const int w = tid >> 6;
  const int cl = lane & 15, g = lane >> 4;
  const int lin = blockIdx.x;            // 512 = 8 xcd * 4 b * 16 tiles
  const int xcd = lin & 7, idx = lin >> 3;
  const int b = xcd * 4 + (idx >> 4);
  const int tile = idx & 15;
  const int tm = tile >> 2, tn = tile & 3;
  const int r0 = tm * 128 + (w >> 1) * 64;
  const int c0 = tn * 128 + (w & 1) * 64;
  const float scale = 0.17677669529663687f;

  const u16* qkb = qk + (size_t)b * 500 * 512;
  float fw[8];
#pragma unroll
  for (int h = 0; h < 8; ++h) fw[h] = pw_g[h] * scale;

  f32x4 acc[4][4];
#pragma unroll
  for (int mi = 0; mi < 4; ++mi)
#pragma unroll
    for (int ni = 0; ni < 4; ++ni) acc[mi][ni] = (f32x4){0.f, 0.f, 0.f, 0.f};

#pragma unroll 2
  for (int kt = 0; kt < 8; ++kt) {
    const int k0 = kt * 32;
    s16x8 af[4], bf[4];
#pragma unroll
    for (int mi = 0; mi < 4; ++mi) {
      int t = r0 + mi * 16 + cl; if (t > 499) t = 499;
      af[mi] = *(const s16x8*)&qkb[(size_t)t * 512 + k0 + g * 8];
    }
#pragma unroll
    for (int ni = 0; ni < 4; ++ni) {
      int s = c0 + ni * 16 + cl; if (s > 499) s = 499;
      bf[ni] = *(const s16x8*)&qkb[(size_t)s * 512 + 256 + k0 + g * 8];
    }
    const f32x4 zf = (f32x4){0.f, 0.f, 0.f, 0.f};
    const float f = fw[kt];
#pragma unroll
    for (int mi = 0; mi < 4; ++mi)
#pragma unroll
      for (int ni = 0; ni < 4; ++ni) {
        f32x4 part = MFMA16(af[mi], bf[ni], zf, 0, 0, 0);
#pragma unroll
        for (int r = 0; r < 4; ++r) acc[mi][ni][r] = fmaf(f, part[r], acc[mi][ni][r]);
      }
  }
#pragma unroll
  for (int mi = 0; mi < 4; ++mi)
#pragma unroll
    for (int ni = 0; ni < 4; ++ni) {
      const int s = c0 + ni * 16 + cl;
#pragma unroll
      for (int r = 0; r < 4; ++r) {
        const int t = r0 + mi * 16 + g * 4 + r;
        if (t < 500 && s < 500) {
          pred[(size_t)(b * 500 + t) * 500 + s] =
              1.f / (1.f + __expf(-acc[mi][ni][r]));
        }
      }
    }
}

// ---------------------------------------------------------------------------
// Kernel 3: value attention, fully wave-local (no LDS, no barriers).
__global__ __launch_bounds__(256) void attn_value(
    const u16* __restrict__ qk, const u16* __restrict__ vt, u16* __restrict__ ctx)
{
  const int tid = threadIdx.x;
  const int w = tid >> 6;
  const int lane = tid & 63;
  const int cl = lane & 15, g = lane >> 4;
  const int lin = blockIdx.x;            // 1024 = 8 xcd * 4 b * 8 h * 4 qg
  const int xcd = lin & 7, idx = lin >> 3;
  const int b = xcd * 4 + (idx >> 5);
  const int rem = idx & 31;
  const int h = rem >> 2, qg = rem & 3;
  const int t0 = qg * 128 + w * 32;
  const float scale = 0.17677669529663687f;

  const u16* qkb = qk + (size_t)b * 500 * 512;
  const u16* vtb = vt + (size_t)b * 256 * 500;

  s16x8 qf[2];
#pragma unroll
  for (int qi = 0; qi < 2; ++qi) {
    int tq = t0 + qi * 16 + cl; if (tq > 499) tq = 499;
    qf[qi] = *(const s16x8*)&qkb[(size_t)tq * 512 + h * 32 + g * 8];
  }
  f32x4 of[2][2];
  float lsum[2] = {0.f, 0.f};
#pragma unroll
  for (int qi = 0; qi < 2; ++qi) {
    of[qi][0] = (f32x4){0.f, 0.f, 0.f, 0.f};
    of[qi][1] = (f32x4){0.f, 0.f, 0.f, 0.f};
  }
  const int sA = (g & 1) * 32 + cl;
  const int sB = sA + 16;
  const bool hiHalf = (lane >= 32);

#pragma unroll 1
  for (int st = 0; st < 8; ++st) {
    const int s0 = st * 64;
    s16x8 kf[4];
#pragma unroll
    for (int si = 0; si < 4; ++si) {
      int sr = s0 + si * 16 + cl; if (sr > 499) sr = 499;
      kf[si] = *(const s16x8*)&qkb[(size_t)sr * 512 + 256 + h * 32 + g * 8];
    }
    s16x8 vf[2][2];
#pragma unroll
    for (int di = 0; di < 2; ++di)
#pragma unroll
      for (int s32 = 0; s32 < 2; ++s32)
        vf[di][s32] = *(const s16x8*)&vtb[(size_t)(h * 32 + di * 16 + cl) * 500 +
                                          s0 + s32 * 32 + g * 8];
    const f32x4 zf = (f32x4){0.f, 0.f, 0.f, 0.f};
    u32 P2[2][4][2];
#pragma unroll
    for (int qi = 0; qi < 2; ++qi) {
#pragma unroll
      for (int si = 0; si < 4; ++si) {
        f32x4 St = MFMA16(kf[si], qf[qi], zf, 0, 0, 0);
        float pv[4];
#pragma unroll
        for (int r = 0; r < 4; ++r) {
          int sidx = s0 + si * 16 + g * 4 + r;
          float e = __expf(St[r] * scale);
          pv[r] = (sidx < 500) ? e : 0.f;
          lsum[qi] += pv[r];
        }
        P2[qi][si][0] = cvt_pk_bf16(pv[0], pv[1]);
        P2[qi][si][1] = cvt_pk_bf16(pv[2], pv[3]);
      }
    }
#pragma unroll
    for (int s32 = 0; s32 < 2; ++s32) {
#pragma unroll
      for (int qi = 0; qi < 2; ++qi) {
        u32 Z0 = hiHalf ? P2[qi][2 * s32 + 1][0] : P2[qi][2 * s32][0];
        u32 Z1 = hiHalf ? P2[qi][2 * s32 + 1][1] : P2[qi][2 * s32][1];
        frag_u fu;
        fu.u[0] = (u32)__shfl((int)Z0, sA);
        fu.u[1] = (u32)__shfl((int)Z1, sA);
        fu.u[2] = (u32)__shfl((int)Z0, sB);
        fu.u[3] = (u32)__shfl((int)Z1, sB);
        of[qi][0] = MFMA16(fu.s, vf[0][s32], of[qi][0], 0, 0, 0);
        of[qi][1] = MFMA16(fu.s, vf[1][s32], of[qi][1], 0, 0, 0);
      }
    }
  }
#pragma unroll
  for (int qi = 0; qi < 2; ++qi) {
    float l2 = lsum[qi] + __shfl_xor(lsum[qi], 16);
    l2 += __shfl_xor(l2, 32);
#pragma unroll
    for (int r = 0; r < 4; ++r) {
      const int tq = t0 + qi * 16 + g * 4 + r;
      if (tq < 500) {
        const float inv = 1.f / __shfl(l2, g * 4 + r);
        ctx[(size_t)(b * 500 + tq) * 256 + h * 32 + cl]      = f2bf(of[qi][0][r] * inv);
        ctx[(size_t)(b * 500 + tq) * 256 + h * 32 + 16 + cl] = f2bf(of[qi][1][r] * inv);
      }
    }
  }
}

// ---------------------------------------------------------------------------
// Kernel 4: proj GEMM, A-stationary (same structure as gemm_qkv; A already bf16).
__global__ __launch_bounds__(512, 2) void gemm_proj(
    const u16* __restrict__ ctx, const u16* __restrict__ WtP,
    const float* __restrict__ bias, float* __restrict__ out)
{
  __shared__ u16 As[64][264];
  const int tid = threadIdx.x;
  const int lane = tid & 63;
  const int w = tid >> 6;
  const int cl = lane & 15, g = lane >> 4;
  const int wm = w >> 2, wn = w & 3;
  const int m0 = blockIdx.x * 64;

#pragma unroll
  for (int it = 0; it < 4; ++it) {
    const int ci = tid + it * 512;
    const int row = ci >> 5;
    const int c8 = (ci & 31) * 8;
    *(u32x4*)&As[row][c8] = *(const u32x4*)&ctx[(size_t)(m0 + row) * 256 + c8];
  }
  __syncthreads();

  s16x8 af[2][8];
#pragma unroll
  for (int mi = 0; mi < 2; ++mi)
#pragma unroll
    for (int kt = 0; kt < 8; ++kt)
      af[mi][kt] = *(const s16x8*)&As[wm * 32 + mi * 16 + cl][kt * 32 + g * 8];

  const int n0 = wn * 64;
  f32x4 acc[2][4];
#pragma unroll
  for (int mi = 0; mi < 2; ++mi)
#pragma unroll
    for (int ni = 0; ni < 4; ++ni) acc[mi][ni] = (f32x4){0.f, 0.f, 0.f, 0.f};
#pragma unroll
  for (int kt = 0; kt < 8; ++kt) {
    s16x8 bf[4];
#pragma unroll
    for (int ni = 0; ni < 4; ++ni)
      bf[ni] = *(const s16x8*)&WtP[(size_t)(n0 + ni * 16 + cl) * 256 + kt * 32 + g * 8];
#pragma unroll
    for (int mi = 0; mi < 2; ++mi)
#pragma unroll
      for (int ni = 0; ni < 4; ++ni)
        acc[mi][ni] = MFMA16(af[mi][kt], bf[ni], acc[mi][ni], 0, 0, 0);
  }
  float bb[4];
#pragma unroll
  for (int ni = 0; ni < 4; ++ni) bb[ni] = bias[n0 + ni * 16 + cl];
#pragma unroll
  for (int mi = 0; mi < 2; ++mi)
#pragma unroll
    for (int ni = 0; ni < 4; ++ni)
#pragma unroll
      for (int r = 0; r < 4; ++r) {
        const int m = m0 + wm * 32 + mi * 16 + g * 4 + r;
        out[(size_t)m * 256 + n0 + ni * 16 + cl] = acc[mi][ni][r] + bb[ni];
      }
}

// ---------------------------------------------------------------------------
extern "C" void kernel_launch(void* const* d_in, const int* in_sizes, int n_in,
                              void* d_out, int out_size, void* d_ws, size_t ws_size,
                              hipStream_t stream)
{
  const float* x      = (const float*)d_in[0];  // [32,500,256]
  const float* W_attn = (const float*)d_in[1];  // [256,768]
  const float* b_attn = (const float*)d_in[2];  // [768]
  const float* p_w    = (const float*)d_in[3];  // [8]
  const float* W_proj = (const float*)d_in[4];  // [256,256]
  const float* b_proj = (const float*)d_in[5];  // [256]

  float* pred   = (float*)d_out;                // [32,500,500]
  float* valout = pred + 8000000;               // [32,500,256]

  u16* qkbuf = (u16*)d_ws;                          // 16,384,000 B
  u16* vt    = (u16*)((char*)d_ws + 16384000);      //  8,192,000 B
  u16* ctx   = (u16*)((char*)d_ws + 24576000);      //  8,192,000 B
  u16* WtA   = ctx;                                 // 394 KB, dead before attn
  u16* WtP   = qkbuf;                               // 131 KB, after attn/pred

  hipLaunchKernelGGL(transpose_w, dim3(4, 12), dim3(256), 0, stream,
                     W_attn, WtA, 256, 768);
  hipLaunchKernelGGL(gemm_qkv, dim3(250), dim3(512), 0, stream,
                     x, WtA, b_attn, qkbuf, vt);
  hipLaunchKernelGGL(pred_gemm, dim3(512), dim3(256), 0, stream,
                     qkbuf, p_w, pred);
  hipLaunchKernelGGL(attn_value, dim3(1024), dim3(256), 0, stream,
                     qkbuf, vt, ctx);
  hipLaunchKernelGGL(transpose_w, dim3(4, 4), dim3(256), 0, stream,
                     W_proj, WtP, 256, 256);
  hipLaunchKernelGGL(gemm_proj, dim3(250), dim3(512), 0, stream,
                     ctx, WtP, b_proj, valout);
}